// Round 1
// baseline (153.036 us; speedup 1.0000x reference)
//
#include <hip/hip_runtime.h>
#include <hip/hip_bf16.h>

// Sizes (fixed by the problem)
#define BB 8
#define TT 2048
#define CC 768
#define DD 64
#define BT (BB * TT)   // 16384

typedef __attribute__((ext_vector_type(8))) short bf16x8;
typedef __attribute__((ext_vector_type(4))) float f32x4;

__device__ __forceinline__ unsigned short f2b(float f) {
  // round-to-nearest-even fp32 -> bf16 (no NaN inputs in this problem)
  unsigned u = __builtin_bit_cast(unsigned, f);
  u += 0x7fffu + ((u >> 16) & 1u);
  return (unsigned short)(u >> 16);
}

// ---------------------------------------------------------------------------
// Kernel 1: W transpose+convert.  wt[c][k] = W_{c/64}[k][c%64] as bf16.
// wt layout: [192][768] bf16
// ---------------------------------------------------------------------------
__global__ __launch_bounds__(256) void wt_kernel(const float* __restrict__ Wq,
                                                 const float* __restrict__ Wk,
                                                 const float* __restrict__ Wv,
                                                 unsigned short* __restrict__ wt) {
  int tid = blockIdx.x * 256 + threadIdx.x; // 0..18431 (192*96)
  if (tid >= 192 * 96) return;
  int k0 = (tid % 96) * 8;
  int c = tid / 96;
  const float* W = (c < 64) ? Wq : (c < 128 ? Wk : Wv);
  int cc = c & 63;
  unsigned short t[8];
#pragma unroll
  for (int e = 0; e < 8; ++e) t[e] = f2b(W[(k0 + e) * 64 + cc]);
  *reinterpret_cast<bf16x8*>(&wt[c * 768 + k0]) = *reinterpret_cast<bf16x8*>(t);
}

// ---------------------------------------------------------------------------
// Kernel 2: QKV projection.  [16384 x 768] fp32 @ [768 x 192] bf16 -> bf16.
// q scaled by D^-0.5 * log2(e)  (folds softmax scale + exp->exp2).
// v written transposed: vt[b][d][t].
// BM=64 per block, 4 waves, each wave: 16 rows x 192 cols (12 MFMA tiles).
// ---------------------------------------------------------------------------
__global__ __launch_bounds__(256) void proj_kernel(const float* __restrict__ x,
                                                   const unsigned short* __restrict__ wt,
                                                   unsigned short* __restrict__ qws,
                                                   unsigned short* __restrict__ kws,
                                                   unsigned short* __restrict__ vtws) {
  __shared__ unsigned short xlds[64][40];   // padded (+8) to spread banks
  __shared__ unsigned short wlds[192][40];
  const int tid = threadIdx.x;
  const int w = tid >> 6;
  const int l = tid & 63;
  const int lo = l & 15, hi = l >> 4;
  const int m0 = blockIdx.x * 64;

  f32x4 acc[12];
#pragma unroll
  for (int i = 0; i < 12; ++i) acc[i] = (f32x4){0.f, 0.f, 0.f, 0.f};

  const int xr = tid >> 2;        // 0..63
  const int xc = (tid & 3) * 8;   // 0,8,16,24

  for (int k0 = 0; k0 < 768; k0 += 32) {
    // stage x tile [64][32] fp32 -> bf16 LDS
    {
      const float* src = x + (size_t)(m0 + xr) * 768 + k0 + xc;
      float a0 = src[0], a1 = src[1], a2 = src[2], a3 = src[3];
      float a4 = src[4], a5 = src[5], a6 = src[6], a7 = src[7];
      unsigned short t[8];
      t[0] = f2b(a0); t[1] = f2b(a1); t[2] = f2b(a2); t[3] = f2b(a3);
      t[4] = f2b(a4); t[5] = f2b(a5); t[6] = f2b(a6); t[7] = f2b(a7);
      *reinterpret_cast<bf16x8*>(&xlds[xr][xc]) = *reinterpret_cast<bf16x8*>(t);
    }
    // stage wt tile [192][32] bf16 (vector copy)
#pragma unroll
    for (int it = 0; it < 3; ++it) {
      int ch = tid + it * 256;            // 0..767
      int row = ch >> 2, cc2 = (ch & 3) * 8;
      *reinterpret_cast<bf16x8*>(&wlds[row][cc2]) =
          *reinterpret_cast<const bf16x8*>(&wt[row * 768 + k0 + cc2]);
    }
    __syncthreads();

    bf16x8 af = *reinterpret_cast<const bf16x8*>(&xlds[w * 16 + lo][hi * 8]);
#pragma unroll
    for (int ct = 0; ct < 12; ++ct) {
      bf16x8 bv = *reinterpret_cast<const bf16x8*>(&wlds[ct * 16 + lo][hi * 8]);
      acc[ct] = __builtin_amdgcn_mfma_f32_16x16x32_bf16(af, bv, acc[ct], 0, 0, 0);
    }
    __syncthreads();
  }

  // epilogue: D layout col=lo (within 16), row=hi*4+r
  const float QS = 0.125f * 1.4426950408889634f;
#pragma unroll
  for (int ct = 0; ct < 12; ++ct) {
    const int mat = ct >> 2;
    const int cc2 = (ct & 3) * 16 + lo;   // 0..63 within its matrix
#pragma unroll
    for (int r = 0; r < 4; ++r) {
      const int m = m0 + w * 16 + hi * 4 + r;
      float v = acc[ct][r];
      if (mat == 0) {
        qws[m * 64 + cc2] = f2b(v * QS);
      } else if (mat == 1) {
        kws[m * 64 + cc2] = f2b(v);
      } else {
        int bb = m >> 11, t = m & 2047;
        vtws[(size_t)(bb * 64 + cc2) * 2048 + t] = f2b(v);
      }
    }
  }
}

// ---------------------------------------------------------------------------
// Kernel 3: causal flash attention.
// QBLK=32, KVBLK=64. 4 waves: wave = par*2+rg ... par in {0,1} = even/odd kv
// tiles (flash-decoding split, merged at end), rg = q-row-group (16 rows each).
// Block bx handles q-tiles bx and 63-bx (uniform 33 kv-tile units/block).
// ---------------------------------------------------------------------------
__global__ __launch_bounds__(256) void attn_kernel(const unsigned short* __restrict__ qws,
                                                   const unsigned short* __restrict__ kws,
                                                   const unsigned short* __restrict__ vtws,
                                                   float* __restrict__ out) {
  __shared__ unsigned short Kl[2][64][72];  // [parity][kv][d], padded
  __shared__ unsigned short Vl[2][64][72];  // [parity][d][kv], padded
  __shared__ unsigned short Pl[4][16][72];  // per-wave P re-fragment buffer
  __shared__ float O2[2][16][68];           // odd-parity O for merge, per rg
  __shared__ float MS[2][2][16];            // [rg][m|s][row]

  const int tid = threadIdx.x;
  const int wv = tid >> 6;
  const int l = tid & 63;
  const int lo = l & 15, hi = l >> 4;
  const int par = wv >> 1;
  const int rg = wv & 1;
  const int b = blockIdx.y;

  const unsigned short* qb = qws + (size_t)b * TT * DD;
  const unsigned short* kb = kws + (size_t)b * TT * DD;
  const unsigned short* vb = vtws + (size_t)b * DD * TT;
  float* ob = out + (size_t)b * TT * DD;

  for (int half = 0; half < 2; ++half) {
    const int qt = half ? (63 - (int)blockIdx.x) : (int)blockIdx.x;
    const int t0 = qt * 32;
    const int nt = (qt >> 1) + 1;          // kv tiles needed for this q-tile
    const int nsteps = (nt + 1) >> 1;

    // Q fragments in registers (already scaled by 0.125*log2e)
    const int qrow = t0 + rg * 16 + lo;
    bf16x8 qf0 = *reinterpret_cast<const bf16x8*>(&qb[qrow * 64 + hi * 8]);
    bf16x8 qf1 = *reinterpret_cast<const bf16x8*>(&qb[qrow * 64 + 32 + hi * 8]);

    f32x4 Oa[4];
#pragma unroll
    for (int n = 0; n < 4; ++n) Oa[n] = (f32x4){0.f, 0.f, 0.f, 0.f};
    float mrow[4] = {-1e30f, -1e30f, -1e30f, -1e30f};
    float srow[4] = {0.f, 0.f, 0.f, 0.f};

    for (int step = 0; step < nsteps; ++step) {
      const int je = 2 * step, jo = je + 1;
      // ---- stage K and Vt tiles for both parities (all 256 threads) ----
      {
        const int kv0 = je * 64;
#pragma unroll
        for (int it = 0; it < 2; ++it) {
          int ch = tid + it * 256;               // 0..511
          int rr = ch >> 3, cc2 = (ch & 7) * 8;  // row 0..63, col offset
          *reinterpret_cast<bf16x8*>(&Kl[0][rr][cc2]) =
              *reinterpret_cast<const bf16x8*>(&kb[(kv0 + rr) * 64 + cc2]);
          *reinterpret_cast<bf16x8*>(&Vl[0][rr][cc2]) =
              *reinterpret_cast<const bf16x8*>(&vb[rr * 2048 + kv0 + cc2]);
        }
        if (jo < nt) {
          const int kv1 = jo * 64;
#pragma unroll
          for (int it = 0; it < 2; ++it) {
            int ch = tid + it * 256;
            int rr = ch >> 3, cc2 = (ch & 7) * 8;
            *reinterpret_cast<bf16x8*>(&Kl[1][rr][cc2]) =
                *reinterpret_cast<const bf16x8*>(&kb[(kv1 + rr) * 64 + cc2]);
            *reinterpret_cast<bf16x8*>(&Vl[1][rr][cc2]) =
                *reinterpret_cast<const bf16x8*>(&vb[rr * 2048 + kv1 + cc2]);
          }
        }
      }
      __syncthreads();

      const int j = par ? jo : je;
      if (j < nt) {
        // ---- S = Q K^T (pre-scaled) ----
        f32x4 S[4];
#pragma unroll
        for (int n = 0; n < 4; ++n) S[n] = (f32x4){0.f, 0.f, 0.f, 0.f};
#pragma unroll
        for (int n = 0; n < 4; ++n) {
          bf16x8 k0v = *reinterpret_cast<const bf16x8*>(&Kl[par][n * 16 + lo][hi * 8]);
          bf16x8 k1v = *reinterpret_cast<const bf16x8*>(&Kl[par][n * 16 + lo][32 + hi * 8]);
          S[n] = __builtin_amdgcn_mfma_f32_16x16x32_bf16(qf0, k0v, S[n], 0, 0, 0);
          S[n] = __builtin_amdgcn_mfma_f32_16x16x32_bf16(qf1, k1v, S[n], 0, 0, 0);
        }
        // ---- causal mask (only the diagonal tile is partial) ----
        if (j == nt - 1) {
#pragma unroll
          for (int n = 0; n < 4; ++n) {
            int kvg = j * 64 + n * 16 + lo;
#pragma unroll
            for (int r = 0; r < 4; ++r) {
              int qg = t0 + rg * 16 + hi * 4 + r;
              if (kvg > qg) S[n][r] = -1e30f;
            }
          }
        }
        // ---- online softmax (exp2 domain) ----
        float fac[4];
#pragma unroll
        for (int r = 0; r < 4; ++r) {
          float v = fmaxf(fmaxf(S[0][r], S[1][r]), fmaxf(S[2][r], S[3][r]));
#pragma unroll
          for (int off = 8; off; off >>= 1) v = fmaxf(v, __shfl_xor(v, off));
          float mn = fmaxf(mrow[r], v);
          fac[r] = exp2f(mrow[r] - mn);
          mrow[r] = mn;
        }
#pragma unroll
        for (int r = 0; r < 4; ++r) {
          float s = 0.f;
#pragma unroll
          for (int n = 0; n < 4; ++n) {
            float p = exp2f(S[n][r] - mrow[r]);
            S[n][r] = p;
            s += p;
          }
#pragma unroll
          for (int off = 8; off; off >>= 1) s += __shfl_xor(s, off);
          srow[r] = srow[r] * fac[r] + s;
#pragma unroll
          for (int n = 0; n < 4; ++n) Oa[n][r] *= fac[r];
        }
        // ---- P -> LDS (bf16), re-fragment for PV ----
#pragma unroll
        for (int n = 0; n < 4; ++n)
#pragma unroll
          for (int r = 0; r < 4; ++r)
            Pl[wv][hi * 4 + r][n * 16 + lo] = f2b(S[n][r]);
        bf16x8 pa0 = *reinterpret_cast<const bf16x8*>(&Pl[wv][lo][hi * 8]);
        bf16x8 pa1 = *reinterpret_cast<const bf16x8*>(&Pl[wv][lo][32 + hi * 8]);
#pragma unroll
        for (int n = 0; n < 4; ++n) {
          bf16x8 v0 = *reinterpret_cast<const bf16x8*>(&Vl[par][n * 16 + lo][hi * 8]);
          bf16x8 v1 = *reinterpret_cast<const bf16x8*>(&Vl[par][n * 16 + lo][32 + hi * 8]);
          Oa[n] = __builtin_amdgcn_mfma_f32_16x16x32_bf16(pa0, v0, Oa[n], 0, 0, 0);
          Oa[n] = __builtin_amdgcn_mfma_f32_16x16x32_bf16(pa1, v1, Oa[n], 0, 0, 0);
        }
      }
      __syncthreads();
    }

    // ---- merge even/odd parity states (flash-decoding style) ----
    if (par == 1) {
      if (lo == 0) {
#pragma unroll
        for (int r = 0; r < 4; ++r) {
          MS[rg][0][hi * 4 + r] = mrow[r];
          MS[rg][1][hi * 4 + r] = srow[r];
        }
      }
#pragma unroll
      for (int n = 0; n < 4; ++n)
#pragma unroll
        for (int r = 0; r < 4; ++r)
          O2[rg][hi * 4 + r][n * 16 + lo] = Oa[n][r];
    }
    __syncthreads();
    if (par == 0) {
#pragma unroll
      for (int r = 0; r < 4; ++r) {
        int row = hi * 4 + r;
        float mo = MS[rg][0][row];
        float so = MS[rg][1][row];
        float M = fmaxf(mrow[r], mo);
        float fe = exp2f(mrow[r] - M);
        float fo = exp2f(mo - M);
        float inv = 1.0f / (srow[r] * fe + so * fo);
#pragma unroll
        for (int n = 0; n < 4; ++n) {
          float val = (Oa[n][r] * fe + O2[rg][row][n * 16 + lo] * fo) * inv;
          ob[(size_t)(t0 + rg * 16 + row) * 64 + n * 16 + lo] = val;
        }
      }
    }
    __syncthreads();
  }
}

// ---------------------------------------------------------------------------
extern "C" void kernel_launch(void* const* d_in, const int* in_sizes, int n_in,
                              void* d_out, int out_size, void* d_ws, size_t ws_size,
                              hipStream_t stream) {
  const float* x = (const float*)d_in[0];
  const float* Wq = (const float*)d_in[1];
  const float* Wk = (const float*)d_in[2];
  const float* Wv = (const float*)d_in[3];
  float* out = (float*)d_out;

  char* ws = (char*)d_ws;
  unsigned short* qws = (unsigned short*)(ws);                              // 2 MB
  unsigned short* kws = (unsigned short*)(ws + (size_t)2 * 1024 * 1024);    // 2 MB
  unsigned short* vtws = (unsigned short*)(ws + (size_t)4 * 1024 * 1024);   // 2 MB
  unsigned short* wt = (unsigned short*)(ws + (size_t)6 * 1024 * 1024);     // 288 KB

  hipLaunchKernelGGL(wt_kernel, dim3(72), dim3(256), 0, stream, Wq, Wk, Wv, wt);
  hipLaunchKernelGGL(proj_kernel, dim3(BT / 64), dim3(256), 0, stream, x, wt, qws, kws, vtws);
  hipLaunchKernelGGL(attn_kernel, dim3(32, 8), dim3(256), 0, stream, qws, kws, vtws, out);
}